// Round 8
// baseline (82.882 us; speedup 1.0000x reference)
//
#include <hip/hip_runtime.h>
#include <hip/hip_bf16.h>

#define NUM_NODES 100000
#define BATCH 4096
#define NNB 64
#define HID 128
#define NHEAD 8
#define HDIM 16
#define TDIM 64
#define RDIM 64
#define START_TC 0.2f
#define END_TC 0.8f
#define NORMS 0.25f

typedef __attribute__((ext_vector_type(4))) float f32x4;
typedef __attribute__((ext_vector_type(8))) short bf16x8;

#define AST 136   // A-tile row stride in shorts (272B: 16B-aligned rows)
#define KST 130   // K tile row stride in shorts (260B: stride/4 % 32 == 1 -> ~conflict-free row reads)
#define APAD 9    // attn_t row stride in floats (odd -> conflict-free scalar writes/reads)

__device__ __forceinline__ short f2bs(float f) {
    unsigned u = __float_as_uint(f);
    u += 0x7fffu + ((u >> 16) & 1u);   // RNE
    return (short)(u >> 16);
}

// Pack weights into MFMA B-fragment order, combined biases, and q0 = t_q(START_T).
__global__ void prep_kernel(const float* __restrict__ t2v_w, const float* __restrict__ t2v_b,
                            const float* __restrict__ tW_k, const float* __restrict__ tb_k,
                            const float* __restrict__ tW_q, const float* __restrict__ tb_q,
                            const float* __restrict__ tW_v, const float* __restrict__ tb_v,
                            const float* __restrict__ rW_k, const float* __restrict__ rb_k,
                            const float* __restrict__ rW_v, const float* __restrict__ rb_v,
                            short* __restrict__ wfrag, float* __restrict__ bias_kv,
                            float* __restrict__ q0_add)
{
    int blk = blockIdx.x, t = threadIdx.x;
    if (blk < 128) {
        // wfrag[((kt*16+nt)*64 + lane)*8 + i] = W[kt*32 + (lane>>4)*8 + i][nt*16 + (lane&15)]
        int idx = blk * 256 + t;
        int i   = idx & 7;
        int ln  = (idx >> 3) & 63;
        int nt  = (idx >> 9) & 15;
        int kt  = idx >> 13;
        int k = kt * 32 + (ln >> 4) * 8 + i;
        int c = nt * 16 + (ln & 15);
        int cc = (c < HID) ? c : c - HID;
        float val;
        if (k < TDIM) val = (c < HID) ? tW_k[k*HID + cc] : tW_v[k*HID + cc];
        else          val = (c < HID) ? rW_k[(k-TDIM)*HID + cc] : rW_v[(k-TDIM)*HID + cc];
        wfrag[idx] = f2bs(val);
    } else if (blk == 128) {
        bias_kv[t] = (t < HID) ? (tb_k[t] + rb_k[t]) : (tb_v[t-HID] + rb_v[t-HID]);
    } else if (t < HID) {
        float s = tb_q[t];
        for (int j = 0; j < TDIM; ++j) {
            float f = START_TC * t2v_w[j] + t2v_b[j];
            float tv = (j == 0) ? f : __sinf(f);
            s += tv * tW_q[j*HID + t];
        }
        q0_add[t] = s;
    }
}

// 512 threads = 8 waves. Wave w owns output cols 32w.. (acc[4][2] = 32 f32/lane).
// rels is streamed once with ZERO reuse -> nontemporal loads keep it from
// evicting the k/v tables (the only data with reuse) out of the 256MB L3.
__launch_bounds__(512, 6)
__global__ void aggr_kernel(const float* __restrict__ k_tab, const float* __restrict__ q_tab,
                            const float* __restrict__ v_tab,
                            const int* __restrict__ nid, const int* __restrict__ neighbors,
                            const float* __restrict__ times, const float* __restrict__ rels,
                            const float* __restrict__ t2v_w, const float* __restrict__ t2v_b,
                            const short* __restrict__ wfrag, const float* __restrict__ bias_kv,
                            const float* __restrict__ q0_add, float* __restrict__ out)
{
    // A-tile (GEMM input) is dead after phase 2; Ksh reuses the same LDS.
    __shared__ __align__(16) short AK[64 * AST];
    __shared__ float q_lds[HID];
    __shared__ float maskadd[NNB];
    __shared__ int   nb_lds[NNB];
    __shared__ float attn_t[NNB][APAD];   // [n][head]
    __shared__ int   anyvalid;

    short* A   = AK;   // stride AST, phases 1-2
    short* Ksh = AK;   // stride KST, phases 3-4

    const int b = blockIdx.x;
    const int t = threadIdx.x;
    const int w = t >> 6;   // wave 0..7
    const int l = t & 63;   // lane

    // ---- phase 0: neighbors / mask / q (consumers all after first barrier) ----
    if (t < 64) {
        nb_lds[t] = neighbors[b*NNB + t];
        float tt = times[b*NNB + t];
        bool valid = (tt >= START_TC) && (tt < END_TC);
        maskadd[t] = valid ? 0.f : -1e30f;
        unsigned long long bal = __ballot(valid);
        if (t == 0) anyvalid = (bal != 0ull) ? 1 : 0;
    } else if (t < 96) {
        int i = t - 64;                 // 0..31
        int q_node = nid[b];
        f32x4 qa = *(const f32x4*)(q_tab + (size_t)q_node*HID + i*4);
        f32x4 qb = *(const f32x4*)(q0_add + i*4);
        *(f32x4*)(q_lds + i*4) = qa + qb;
    }

    // ---- phase 1: stage A-tile = [t2v(times) | rels], wave-specialized ----
    if (w < 4) {
        // waves 0-3: t2v columns 16w..16w+15 for row l (pure VALU after one coalesced load)
        float tt = times[b*NNB + l];
        int c0 = w * 16;
        bf16x8 v0, v1;
        #pragma unroll
        for (int u = 0; u < 8; ++u) {
            int j = c0 + u;
            float f = fmaf(tt, t2v_w[j], t2v_b[j]);
            v0[u] = f2bs((j == 0) ? f : __sinf(f));
        }
        #pragma unroll
        for (int u = 0; u < 8; ++u) {
            int j = c0 + 8 + u;
            float f = fmaf(tt, t2v_w[j], t2v_b[j]);
            v1[u] = f2bs(__sinf(f));
        }
        *(bf16x8*)(&A[l*AST + c0])     = v0;
        *(bf16x8*)(&A[l*AST + c0 + 8]) = v1;
    } else {
        // waves 4-7: rels columns 16s..16s+15 for row l (nontemporal streaming loads)
        int s = w - 4;
        const f32x4* rp = (const f32x4*)(rels + ((size_t)b*NNB + l)*RDIM + s*16);
        f32x4 r0 = __builtin_nontemporal_load(rp);
        f32x4 r1 = __builtin_nontemporal_load(rp + 1);
        f32x4 r2 = __builtin_nontemporal_load(rp + 2);
        f32x4 r3 = __builtin_nontemporal_load(rp + 3);
        bf16x8 o0, o1;
        #pragma unroll
        for (int e = 0; e < 4; ++e) {
            o0[e]   = f2bs(r0[e]);  o0[e+4] = f2bs(r1[e]);
            o1[e]   = f2bs(r2[e]);  o1[e+4] = f2bs(r3[e]);
        }
        *(bf16x8*)(&A[l*AST + TDIM + s*16])     = o0;
        *(bf16x8*)(&A[l*AST + TDIM + s*16 + 8]) = o1;
    }
    __syncthreads();

    // ---- phase 2: GEMM [64x128] @ [128x256]; wave w owns cols 32w..32w+31 ----
    f32x4 acc[4][2];
    #pragma unroll
    for (int mt = 0; mt < 4; ++mt)
        #pragma unroll
        for (int j = 0; j < 2; ++j)
            acc[mt][j] = (f32x4){0.f, 0.f, 0.f, 0.f};

    const bf16x8* wf = (const bf16x8*)wfrag;
    #pragma unroll
    for (int kt = 0; kt < 4; ++kt) {
        bf16x8 af[4], bfrag[2];
        int kcol = kt*32 + (l >> 4)*8;
        #pragma unroll
        for (int mt = 0; mt < 4; ++mt)
            af[mt] = *(const bf16x8*)(&A[(mt*16 + (l & 15))*AST + kcol]);
        #pragma unroll
        for (int j = 0; j < 2; ++j)
            bfrag[j] = wf[(kt*16 + (2*w + j))*64 + l];
        #pragma unroll
        for (int mt = 0; mt < 4; ++mt)
            #pragma unroll
            for (int j = 0; j < 2; ++j)
                acc[mt][j] = __builtin_amdgcn_mfma_f32_16x16x32_bf16(af[mt], bfrag[j], acc[mt][j], 0, 0, 0);
    }
    __syncthreads();   // A is dead; Ksh may now overwrite it

    // ---- phase 3: gather table rows + bias.
    // waves 0-3: k -> bf16 Ksh (LDS). waves 4-7: v stays f32 in acc registers.
    if (w < 4) {
        int cw = w * 32;
        float biasr[2];
        #pragma unroll
        for (int j = 0; j < 2; ++j)
            biasr[j] = bias_kv[cw + j*16 + (l & 15)];
        #pragma unroll
        for (int mt = 0; mt < 4; ++mt) {
            #pragma unroll
            for (int i = 0; i < 4; ++i) {
                int n = mt*16 + ((l >> 4) << 2) + i;
                const float* trow = k_tab + (size_t)nb_lds[n]*HID;
                #pragma unroll
                for (int j = 0; j < 2; ++j) {
                    int col = cw + j*16 + (l & 15);
                    Ksh[n*KST + col] = f2bs(acc[mt][j][i] + biasr[j] + trow[col]);
                }
            }
        }
    } else {
        int cw = (w - 4) * 32;
        float biasr[2];
        #pragma unroll
        for (int j = 0; j < 2; ++j)
            biasr[j] = bias_kv[HID + cw + j*16 + (l & 15)];
        #pragma unroll
        for (int mt = 0; mt < 4; ++mt) {
            #pragma unroll
            for (int i = 0; i < 4; ++i) {
                int n = mt*16 + ((l >> 4) << 2) + i;
                const float* trow = v_tab + (size_t)nb_lds[n]*HID;
                #pragma unroll
                for (int j = 0; j < 2; ++j)
                    acc[mt][j][i] += biasr[j] + trow[cw + j*16 + (l & 15)];
            }
        }
    }
    __syncthreads();

    // ---- phase 4: scores + softmax. lane l = neighbor l; wave w = head w ----
    {
        const short* krow = &Ksh[l*KST + w*16];
        float s = 0.f;
        #pragma unroll
        for (int e = 0; e < 8; ++e) {
            unsigned u = *(const unsigned*)(&krow[2*e]);
            float k0 = __uint_as_float(u << 16);
            float k1 = __uint_as_float(u & 0xffff0000u);
            s = fmaf(q_lds[w*16 + 2*e],     k0, s);
            s = fmaf(q_lds[w*16 + 2*e + 1], k1, s);
        }
        float sc = s * NORMS + maskadd[l];
        float m = sc;
        #pragma unroll
        for (int off = 1; off <= 32; off <<= 1)
            m = fmaxf(m, __shfl_xor(m, off));
        float e = __expf(sc - m);
        float sum = e;
        #pragma unroll
        for (int off = 1; off <= 32; off <<= 1)
            sum += __shfl_xor(sum, off);
        attn_t[l][w] = e / sum;
    }
    __syncthreads();

    // ---- phase 5: PV in registers (waves 4-7 hold v) + cross-group reduce ----
    if (w >= 4) {
        int g = w - 4;
        float p[2] = {0.f, 0.f};
        #pragma unroll
        for (int mt = 0; mt < 4; ++mt) {
            #pragma unroll
            for (int i = 0; i < 4; ++i) {
                int n = mt*16 + ((l >> 4) << 2) + i;
                #pragma unroll
                for (int j = 0; j < 2; ++j)
                    p[j] = fmaf(attn_t[n][2*g + j], acc[mt][j][i], p[j]);
            }
        }
        #pragma unroll
        for (int j = 0; j < 2; ++j) {
            p[j] += __shfl_xor(p[j], 16);
            p[j] += __shfl_xor(p[j], 32);
        }
        if (l < 16) {
            #pragma unroll
            for (int j = 0; j < 2; ++j) {
                int col = g*32 + j*16 + l;
                __builtin_nontemporal_store(anyvalid ? p[j] : 0.f,
                                            out + (size_t)b*HID + col);
            }
        }
    }
}

extern "C" void kernel_launch(void* const* d_in, const int* in_sizes, int n_in,
                              void* d_out, int out_size, void* d_ws, size_t ws_size,
                              hipStream_t stream)
{
    const float* k_tab = (const float*)d_in[0];
    const float* q_tab = (const float*)d_in[1];
    const float* v_tab = (const float*)d_in[2];
    const int*   nid   = (const int*)d_in[3];
    const int*   neighbors = (const int*)d_in[4];
    const float* times = (const float*)d_in[5];
    const float* rels  = (const float*)d_in[6];
    const float* t2v_w = (const float*)d_in[7];
    const float* t2v_b = (const float*)d_in[8];
    const float* tW_k  = (const float*)d_in[9];
    const float* tb_k  = (const float*)d_in[10];
    const float* tW_q  = (const float*)d_in[11];
    const float* tb_q  = (const float*)d_in[12];
    const float* tW_v  = (const float*)d_in[13];
    const float* tb_v  = (const float*)d_in[14];
    const float* rW_k  = (const float*)d_in[15];
    const float* rb_k  = (const float*)d_in[16];
    const float* rW_v  = (const float*)d_in[17];
    const float* rb_v  = (const float*)d_in[18];

    short* wfrag   = (short*)d_ws;                          // 32768 bf16 = 64KB
    float* bias_kv = (float*)((char*)d_ws + 65536);         // 256 f32
    float* q0_add  = (float*)((char*)d_ws + 65536 + 1024);  // 128 f32

    prep_kernel<<<130, 256, 0, stream>>>(t2v_w, t2v_b, tW_k, tb_k, tW_q, tb_q,
                                         tW_v, tb_v, rW_k, rb_k, rW_v, rb_v,
                                         wfrag, bias_kv, q0_add);
    aggr_kernel<<<BATCH, 512, 0, stream>>>(k_tab, q_tab, v_tab, nid, neighbors,
                                           times, rels, t2v_w, t2v_b,
                                           wfrag, bias_kv, q0_add, (float*)d_out);
}

// Round 9
// 75.244 us; speedup vs baseline: 1.1015x; 1.1015x over previous
//
#include <hip/hip_runtime.h>
#include <hip/hip_bf16.h>

#define NUM_NODES 100000
#define BATCH 4096
#define NNB 64
#define HID 128
#define NHEAD 8
#define HDIM 16
#define TDIM 64
#define RDIM 64
#define START_TC 0.2f
#define END_TC 0.8f
#define NORMS 0.25f

typedef __attribute__((ext_vector_type(4))) float f32x4;
typedef __attribute__((ext_vector_type(8))) short bf16x8;

#define AST 136   // A-tile row stride in shorts (272B: 16B-aligned rows)
#define KST 130   // K tile row stride in shorts (260B: stride/4 % 32 == 1 -> ~conflict-free row reads)
#define APAD 9    // attn_t row stride in floats (odd -> conflict-free scalar writes/reads)

__device__ __forceinline__ short f2bs(float f) {
    unsigned u = __float_as_uint(f);
    u += 0x7fffu + ((u >> 16) & 1u);   // RNE
    return (short)(u >> 16);
}

// Pack weights into MFMA B-fragment order, combined biases, and q0 = t_q(START_T).
__global__ void prep_kernel(const float* __restrict__ t2v_w, const float* __restrict__ t2v_b,
                            const float* __restrict__ tW_k, const float* __restrict__ tb_k,
                            const float* __restrict__ tW_q, const float* __restrict__ tb_q,
                            const float* __restrict__ tW_v, const float* __restrict__ tb_v,
                            const float* __restrict__ rW_k, const float* __restrict__ rb_k,
                            const float* __restrict__ rW_v, const float* __restrict__ rb_v,
                            short* __restrict__ wfrag, float* __restrict__ bias_kv,
                            float* __restrict__ q0_add)
{
    int blk = blockIdx.x, t = threadIdx.x;
    if (blk < 128) {
        // wfrag[((kt*16+nt)*64 + lane)*8 + i] = W[kt*32 + (lane>>4)*8 + i][nt*16 + (lane&15)]
        int idx = blk * 256 + t;
        int i   = idx & 7;
        int ln  = (idx >> 3) & 63;
        int nt  = (idx >> 9) & 15;
        int kt  = idx >> 13;
        int k = kt * 32 + (ln >> 4) * 8 + i;
        int c = nt * 16 + (ln & 15);
        int cc = (c < HID) ? c : c - HID;
        float val;
        if (k < TDIM) val = (c < HID) ? tW_k[k*HID + cc] : tW_v[k*HID + cc];
        else          val = (c < HID) ? rW_k[(k-TDIM)*HID + cc] : rW_v[(k-TDIM)*HID + cc];
        wfrag[idx] = f2bs(val);
    } else if (blk == 128) {
        bias_kv[t] = (t < HID) ? (tb_k[t] + rb_k[t]) : (tb_v[t-HID] + rb_v[t-HID]);
    } else if (t < HID) {
        float s = tb_q[t];
        for (int j = 0; j < TDIM; ++j) {
            float f = START_TC * t2v_w[j] + t2v_b[j];
            float tv = (j == 0) ? f : __sinf(f);
            s += tv * tW_q[j*HID + t];
        }
        q0_add[t] = s;
    }
}

// 512 threads = 8 waves. Wave w owns output cols 32w.. (acc[4][2] = 32 f32/lane).
// ~40% of neighbors fall outside the time window: their contribution is exactly
// zero after softmax masking, so we SKIP their rels stream and k/v table gather
// (predicated loads -> masked lanes fetch nothing). Masked Ksh rows / A rows are
// stored as finite zeros so scores stay NaN-free.
__launch_bounds__(512, 6)
__global__ void aggr_kernel(const float* __restrict__ k_tab, const float* __restrict__ q_tab,
                            const float* __restrict__ v_tab,
                            const int* __restrict__ nid, const int* __restrict__ neighbors,
                            const float* __restrict__ times, const float* __restrict__ rels,
                            const float* __restrict__ t2v_w, const float* __restrict__ t2v_b,
                            const short* __restrict__ wfrag, const float* __restrict__ bias_kv,
                            const float* __restrict__ q0_add, float* __restrict__ out)
{
    // A-tile (GEMM input) is dead after phase 2; Ksh reuses the same LDS.
    __shared__ __align__(16) short AK[64 * AST];
    __shared__ float q_lds[HID];
    __shared__ float maskadd[NNB];
    __shared__ int   nb_lds[NNB];
    __shared__ float attn_t[NNB][APAD];   // [n][head]
    __shared__ int   anyvalid;

    short* A   = AK;   // stride AST, phases 1-2
    short* Ksh = AK;   // stride KST, phases 3-4

    const int b = blockIdx.x;
    const int t = threadIdx.x;
    const int w = t >> 6;   // wave 0..7
    const int l = t & 63;   // lane

    // ---- phase 0: neighbors / mask / q (consumers all after first barrier) ----
    if (t < 64) {
        nb_lds[t] = neighbors[b*NNB + t];
        float tt = times[b*NNB + t];
        bool valid = (tt >= START_TC) && (tt < END_TC);
        maskadd[t] = valid ? 0.f : -1e30f;
        unsigned long long bal = __ballot(valid);
        if (t == 0) anyvalid = (bal != 0ull) ? 1 : 0;
    } else if (t < 96) {
        int i = t - 64;                 // 0..31
        int q_node = nid[b];
        f32x4 qa = *(const f32x4*)(q_tab + (size_t)q_node*HID + i*4);
        f32x4 qb = *(const f32x4*)(q0_add + i*4);
        *(f32x4*)(q_lds + i*4) = qa + qb;
    }

    // ---- phase 1: stage A-tile = [t2v(times) | rels], wave-specialized,
    //      masked rows staged as zeros (skip sin VALU + rels traffic) ----
    {
        float tt = times[b*NNB + l];    // coalesced per wave; L1-hot across waves
        bool valid = (tt >= START_TC) && (tt < END_TC);
        if (w < 4) {
            int c0 = w * 16;
            bf16x8 v0 = (bf16x8){0,0,0,0,0,0,0,0};
            bf16x8 v1 = (bf16x8){0,0,0,0,0,0,0,0};
            if (valid) {
                #pragma unroll
                for (int u = 0; u < 8; ++u) {
                    int j = c0 + u;
                    float f = fmaf(tt, t2v_w[j], t2v_b[j]);
                    v0[u] = f2bs((j == 0) ? f : __sinf(f));
                }
                #pragma unroll
                for (int u = 0; u < 8; ++u) {
                    int j = c0 + 8 + u;
                    float f = fmaf(tt, t2v_w[j], t2v_b[j]);
                    v1[u] = f2bs(__sinf(f));
                }
            }
            *(bf16x8*)(&A[l*AST + c0])     = v0;
            *(bf16x8*)(&A[l*AST + c0 + 8]) = v1;
        } else {
            int s = w - 4;
            bf16x8 o0 = (bf16x8){0,0,0,0,0,0,0,0};
            bf16x8 o1 = (bf16x8){0,0,0,0,0,0,0,0};
            if (valid) {
                const float* rp = rels + ((size_t)b*NNB + l)*RDIM + s*16;
                f32x4 r0 = *(const f32x4*)(rp);
                f32x4 r1 = *(const f32x4*)(rp + 4);
                f32x4 r2 = *(const f32x4*)(rp + 8);
                f32x4 r3 = *(const f32x4*)(rp + 12);
                #pragma unroll
                for (int e = 0; e < 4; ++e) {
                    o0[e]   = f2bs(r0[e]);  o0[e+4] = f2bs(r1[e]);
                    o1[e]   = f2bs(r2[e]);  o1[e+4] = f2bs(r3[e]);
                }
            }
            *(bf16x8*)(&A[l*AST + TDIM + s*16])     = o0;
            *(bf16x8*)(&A[l*AST + TDIM + s*16 + 8]) = o1;
        }
    }
    __syncthreads();

    // ---- phase 2: GEMM [64x128] @ [128x256]; wave w owns cols 32w..32w+31 ----
    f32x4 acc[4][2];
    #pragma unroll
    for (int mt = 0; mt < 4; ++mt)
        #pragma unroll
        for (int j = 0; j < 2; ++j)
            acc[mt][j] = (f32x4){0.f, 0.f, 0.f, 0.f};

    const bf16x8* wf = (const bf16x8*)wfrag;
    #pragma unroll
    for (int kt = 0; kt < 4; ++kt) {
        bf16x8 af[4], bfrag[2];
        int kcol = kt*32 + (l >> 4)*8;
        #pragma unroll
        for (int mt = 0; mt < 4; ++mt)
            af[mt] = *(const bf16x8*)(&A[(mt*16 + (l & 15))*AST + kcol]);
        #pragma unroll
        for (int j = 0; j < 2; ++j)
            bfrag[j] = wf[(kt*16 + (2*w + j))*64 + l];
        #pragma unroll
        for (int mt = 0; mt < 4; ++mt)
            #pragma unroll
            for (int j = 0; j < 2; ++j)
                acc[mt][j] = __builtin_amdgcn_mfma_f32_16x16x32_bf16(af[mt], bfrag[j], acc[mt][j], 0, 0, 0);
    }
    __syncthreads();   // A is dead; Ksh may now overwrite it

    // ---- phase 3: gather table rows + bias, SKIPPING masked neighbors.
    // waves 0-3: k -> bf16 Ksh (LDS, zeros when masked). waves 4-7: v stays in acc.
    if (w < 4) {
        int cw = w * 32;
        float biasr[2];
        #pragma unroll
        for (int j = 0; j < 2; ++j)
            biasr[j] = bias_kv[cw + j*16 + (l & 15)];
        #pragma unroll
        for (int mt = 0; mt < 4; ++mt) {
            #pragma unroll
            for (int i = 0; i < 4; ++i) {
                int n = mt*16 + ((l >> 4) << 2) + i;
                bool nv = (maskadd[n] == 0.f);
                float v0 = 0.f, v1 = 0.f;
                if (nv) {
                    const float* trow = k_tab + (size_t)nb_lds[n]*HID + cw + (l & 15);
                    v0 = acc[mt][0][i] + biasr[0] + trow[0];
                    v1 = acc[mt][1][i] + biasr[1] + trow[16];
                }
                Ksh[n*KST + cw +      (l & 15)] = f2bs(v0);
                Ksh[n*KST + cw + 16 + (l & 15)] = f2bs(v1);
            }
        }
    } else {
        int cw = (w - 4) * 32;
        float biasr[2];
        #pragma unroll
        for (int j = 0; j < 2; ++j)
            biasr[j] = bias_kv[HID + cw + j*16 + (l & 15)];
        #pragma unroll
        for (int mt = 0; mt < 4; ++mt) {
            #pragma unroll
            for (int i = 0; i < 4; ++i) {
                int n = mt*16 + ((l >> 4) << 2) + i;
                bool nv = (maskadd[n] == 0.f);
                if (nv) {
                    const float* trow = v_tab + (size_t)nb_lds[n]*HID + cw + (l & 15);
                    acc[mt][0][i] += biasr[0] + trow[0];
                    acc[mt][1][i] += biasr[1] + trow[16];
                }
            }
        }
    }
    __syncthreads();

    // ---- phase 4: scores + softmax. lane l = neighbor l; wave w = head w ----
    {
        const short* krow = &Ksh[l*KST + w*16];
        float s = 0.f;
        #pragma unroll
        for (int e = 0; e < 8; ++e) {
            unsigned u = *(const unsigned*)(&krow[2*e]);
            float k0 = __uint_as_float(u << 16);
            float k1 = __uint_as_float(u & 0xffff0000u);
            s = fmaf(q_lds[w*16 + 2*e],     k0, s);
            s = fmaf(q_lds[w*16 + 2*e + 1], k1, s);
        }
        float sc = s * NORMS + maskadd[l];
        float m = sc;
        #pragma unroll
        for (int off = 1; off <= 32; off <<= 1)
            m = fmaxf(m, __shfl_xor(m, off));
        float e = __expf(sc - m);
        float sum = e;
        #pragma unroll
        for (int off = 1; off <= 32; off <<= 1)
            sum += __shfl_xor(sum, off);
        attn_t[l][w] = e / sum;
    }
    __syncthreads();

    // ---- phase 5: PV in registers (waves 4-7 hold v) + cross-group reduce ----
    if (w >= 4) {
        int g = w - 4;
        float p[2] = {0.f, 0.f};
        #pragma unroll
        for (int mt = 0; mt < 4; ++mt) {
            #pragma unroll
            for (int i = 0; i < 4; ++i) {
                int n = mt*16 + ((l >> 4) << 2) + i;
                #pragma unroll
                for (int j = 0; j < 2; ++j)
                    p[j] = fmaf(attn_t[n][2*g + j], acc[mt][j][i], p[j]);
            }
        }
        #pragma unroll
        for (int j = 0; j < 2; ++j) {
            p[j] += __shfl_xor(p[j], 16);
            p[j] += __shfl_xor(p[j], 32);
        }
        if (l < 16) {
            #pragma unroll
            for (int j = 0; j < 2; ++j) {
                int col = g*32 + j*16 + l;
                out[(size_t)b*HID + col] = anyvalid ? p[j] : 0.f;
            }
        }
    }
}

extern "C" void kernel_launch(void* const* d_in, const int* in_sizes, int n_in,
                              void* d_out, int out_size, void* d_ws, size_t ws_size,
                              hipStream_t stream)
{
    const float* k_tab = (const float*)d_in[0];
    const float* q_tab = (const float*)d_in[1];
    const float* v_tab = (const float*)d_in[2];
    const int*   nid   = (const int*)d_in[3];
    const int*   neighbors = (const int*)d_in[4];
    const float* times = (const float*)d_in[5];
    const float* rels  = (const float*)d_in[6];
    const float* t2v_w = (const float*)d_in[7];
    const float* t2v_b = (const float*)d_in[8];
    const float* tW_k  = (const float*)d_in[9];
    const float* tb_k  = (const float*)d_in[10];
    const float* tW_q  = (const float*)d_in[11];
    const float* tb_q  = (const float*)d_in[12];
    const float* tW_v  = (const float*)d_in[13];
    const float* tb_v  = (const float*)d_in[14];
    const float* rW_k  = (const float*)d_in[15];
    const float* rb_k  = (const float*)d_in[16];
    const float* rW_v  = (const float*)d_in[17];
    const float* rb_v  = (const float*)d_in[18];

    short* wfrag   = (short*)d_ws;                          // 32768 bf16 = 64KB
    float* bias_kv = (float*)((char*)d_ws + 65536);         // 256 f32
    float* q0_add  = (float*)((char*)d_ws + 65536 + 1024);  // 128 f32

    prep_kernel<<<130, 256, 0, stream>>>(t2v_w, t2v_b, tW_k, tb_k, tW_q, tb_q,
                                         tW_v, tb_v, rW_k, rb_k, rW_v, rb_v,
                                         wfrag, bias_kv, q0_add);
    aggr_kernel<<<BATCH, 512, 0, stream>>>(k_tab, q_tab, v_tab, nid, neighbors,
                                           times, rels, t2v_w, t2v_b,
                                           wfrag, bias_kv, q0_add, (float*)d_out);
}

// Round 10
// 69.529 us; speedup vs baseline: 1.1920x; 1.0822x over previous
//
#include <hip/hip_runtime.h>
#include <hip/hip_bf16.h>

#define NUM_NODES 100000
#define BATCH 4096
#define NNB 64
#define HID 128
#define NHEAD 8
#define HDIM 16
#define TDIM 64
#define RDIM 64
#define START_TC 0.2f
#define END_TC 0.8f
#define NORMS 0.25f

typedef __attribute__((ext_vector_type(4))) float f32x4;
typedef __attribute__((ext_vector_type(8))) short bf16x8;

#define AST 136   // A-tile row stride in shorts (272B: 16B-aligned rows)
#define APAD 9    // attn_t row stride in floats (odd -> conflict-free)

__device__ __forceinline__ short f2bs(float f) {
    unsigned u = __float_as_uint(f);
    u += 0x7fffu + ((u >> 16) & 1u);   // RNE
    return (short)(u >> 16);
}

// Sum across each 16-lane row via DPP row_ror (pure VALU, no LDS pipe).
__device__ __forceinline__ float rowsum16(float x) {
    x += __int_as_float(__builtin_amdgcn_update_dpp(0, __float_as_int(x), 0x121, 0xf, 0xf, true));
    x += __int_as_float(__builtin_amdgcn_update_dpp(0, __float_as_int(x), 0x122, 0xf, 0xf, true));
    x += __int_as_float(__builtin_amdgcn_update_dpp(0, __float_as_int(x), 0x124, 0xf, 0xf, true));
    x += __int_as_float(__builtin_amdgcn_update_dpp(0, __float_as_int(x), 0x128, 0xf, 0xf, true));
    return x;
}

// Pack weights into MFMA B-fragment order, combined biases, and q0 = t_q(START_T).
__global__ void prep_kernel(const float* __restrict__ t2v_w, const float* __restrict__ t2v_b,
                            const float* __restrict__ tW_k, const float* __restrict__ tb_k,
                            const float* __restrict__ tW_q, const float* __restrict__ tb_q,
                            const float* __restrict__ tW_v, const float* __restrict__ tb_v,
                            const float* __restrict__ rW_k, const float* __restrict__ rb_k,
                            const float* __restrict__ rW_v, const float* __restrict__ rb_v,
                            short* __restrict__ wfrag, float* __restrict__ bias_kv,
                            float* __restrict__ q0_add)
{
    int blk = blockIdx.x, t = threadIdx.x;
    if (blk < 128) {
        int idx = blk * 256 + t;
        int i   = idx & 7;
        int ln  = (idx >> 3) & 63;
        int nt  = (idx >> 9) & 15;
        int kt  = idx >> 13;
        int k = kt * 32 + (ln >> 4) * 8 + i;
        int c = nt * 16 + (ln & 15);
        int cc = (c < HID) ? c : c - HID;
        float val;
        if (k < TDIM) val = (c < HID) ? tW_k[k*HID + cc] : tW_v[k*HID + cc];
        else          val = (c < HID) ? rW_k[(k-TDIM)*HID + cc] : rW_v[(k-TDIM)*HID + cc];
        wfrag[idx] = f2bs(val);
    } else if (blk == 128) {
        bias_kv[t] = (t < HID) ? (tb_k[t] + rb_k[t]) : (tb_v[t-HID] + rb_v[t-HID]);
    } else if (t < HID) {
        float s = tb_q[t];
        for (int j = 0; j < TDIM; ++j) {
            float f = START_TC * t2v_w[j] + t2v_b[j];
            float tv = (j == 0) ? f : __sinf(f);
            s += tv * tW_q[j*HID + t];
        }
        q0_add[t] = s;
    }
}

// 512 threads = 8 waves. Wave w owns output cols 32w..32w+31 = heads {2w,2w+1}
// for w<4 (k path) resp. v path for w>=4. Scores+softmax computed IN REGISTERS
// by waves 0-3 (DPP 16-lane reduce over d) while waves 4-7 gather v: the two
// halves overlap, no Ksh staging, only TWO barriers total.
__launch_bounds__(512, 4)
__global__ void aggr_kernel(const float* __restrict__ k_tab, const float* __restrict__ q_tab,
                            const float* __restrict__ v_tab,
                            const int* __restrict__ nid, const int* __restrict__ neighbors,
                            const float* __restrict__ times, const float* __restrict__ rels,
                            const float* __restrict__ t2v_w, const float* __restrict__ t2v_b,
                            const short* __restrict__ wfrag, const float* __restrict__ bias_kv,
                            const float* __restrict__ q0_add, float* __restrict__ out)
{
    __shared__ __align__(16) short A[64 * AST];
    __shared__ float q_lds[HID];
    __shared__ float maskadd[NNB];
    __shared__ int   nb_lds[NNB];
    __shared__ float attn_t[NNB][APAD];   // [n][head]
    __shared__ int   anyvalid;

    const int b = blockIdx.x;
    const int t = threadIdx.x;
    const int w = t >> 6;   // wave 0..7
    const int l = t & 63;   // lane
    const int d = l & 15;   // dim-within-head / col-within-16
    const int g = l >> 4;   // 16-lane group 0..3

    // ---- phase 0: neighbors / mask / q (consumers all after barrier 1) ----
    if (t < 64) {
        nb_lds[t] = neighbors[b*NNB + t];
        float tt = times[b*NNB + t];
        bool valid = (tt >= START_TC) && (tt < END_TC);
        maskadd[t] = valid ? 0.f : -1e30f;
        unsigned long long bal = __ballot(valid);
        if (t == 0) anyvalid = (bal != 0ull) ? 1 : 0;
    } else if (t < 96) {
        int i = t - 64;                 // 0..31
        int q_node = nid[b];
        f32x4 qa = *(const f32x4*)(q_tab + (size_t)q_node*HID + i*4);
        f32x4 qb = *(const f32x4*)(q0_add + i*4);
        *(f32x4*)(q_lds + i*4) = qa + qb;
    }

    // ---- phase 1: stage A-tile = [t2v(times) | rels], wave-specialized ----
    if (w < 4) {
        float tt = times[b*NNB + l];
        int c0 = w * 16;
        bf16x8 v0, v1;
        #pragma unroll
        for (int u = 0; u < 8; ++u) {
            int j = c0 + u;
            float f = fmaf(tt, t2v_w[j], t2v_b[j]);
            v0[u] = f2bs((j == 0) ? f : __sinf(f));
        }
        #pragma unroll
        for (int u = 0; u < 8; ++u) {
            int j = c0 + 8 + u;
            float f = fmaf(tt, t2v_w[j], t2v_b[j]);
            v1[u] = f2bs(__sinf(f));
        }
        *(bf16x8*)(&A[l*AST + c0])     = v0;
        *(bf16x8*)(&A[l*AST + c0 + 8]) = v1;
    } else {
        int s = w - 4;
        const float* rp = rels + ((size_t)b*NNB + l)*RDIM + s*16;
        f32x4 r0 = *(const f32x4*)(rp);
        f32x4 r1 = *(const f32x4*)(rp + 4);
        f32x4 r2 = *(const f32x4*)(rp + 8);
        f32x4 r3 = *(const f32x4*)(rp + 12);
        bf16x8 o0, o1;
        #pragma unroll
        for (int e = 0; e < 4; ++e) {
            o0[e]   = f2bs(r0[e]);  o0[e+4] = f2bs(r1[e]);
            o1[e]   = f2bs(r2[e]);  o1[e+4] = f2bs(r3[e]);
        }
        *(bf16x8*)(&A[l*AST + TDIM + s*16])     = o0;
        *(bf16x8*)(&A[l*AST + TDIM + s*16 + 8]) = o1;
    }
    __syncthreads();   // barrier 1: A, q_lds, maskadd, nb_lds ready

    // ---- phase 2: GEMM [64x128] @ [128x256]; wave w owns cols 32w..32w+31 ----
    f32x4 acc[4][2];
    #pragma unroll
    for (int mt = 0; mt < 4; ++mt)
        #pragma unroll
        for (int j = 0; j < 2; ++j)
            acc[mt][j] = (f32x4){0.f, 0.f, 0.f, 0.f};

    const bf16x8* wf = (const bf16x8*)wfrag;
    #pragma unroll
    for (int kt = 0; kt < 4; ++kt) {
        bf16x8 af[4], bfrag[2];
        int kcol = kt*32 + g*8;     // (l>>4)*8
        #pragma unroll
        for (int mt = 0; mt < 4; ++mt)
            af[mt] = *(const bf16x8*)(&A[(mt*16 + d)*AST + kcol]);
        #pragma unroll
        for (int j = 0; j < 2; ++j)
            bfrag[j] = wf[(kt*16 + (2*w + j))*64 + l];
        #pragma unroll
        for (int mt = 0; mt < 4; ++mt)
            #pragma unroll
            for (int j = 0; j < 2; ++j)
                acc[mt][j] = __builtin_amdgcn_mfma_f32_16x16x32_bf16(af[mt], bfrag[j], acc[mt][j], 0, 0, 0);
    }
    // NO barrier: A is not written again; k and v halves proceed independently.

    if (w < 4) {
        // ---- k path (waves 0-3): gather k rows, scores + softmax in registers.
        // acc[mt][j][i] = k[n][cw + j*16 + d], n = mt*16 + g*4 + i, head hj = 2w+j.
        const int cw = w * 32;
        const float q0 = q_lds[cw + d];
        const float q1 = q_lds[cw + 16 + d];
        const float bk0 = bias_kv[cw + d];
        const float bk1 = bias_kv[cw + 16 + d];

        float e0[4][4], e1[4][4];
        #pragma unroll
        for (int mt = 0; mt < 4; ++mt) {
            float k0v[4], k1v[4];
            #pragma unroll
            for (int i = 0; i < 4; ++i) {
                int n = mt*16 + g*4 + i;
                const float* trow = k_tab + (size_t)nb_lds[n]*HID + cw + d;
                k0v[i] = trow[0];
                k1v[i] = trow[16];
            }
            #pragma unroll
            for (int i = 0; i < 4; ++i) {
                float kk0 = acc[mt][0][i] + bk0 + k0v[i];
                float kk1 = acc[mt][1][i] + bk1 + k1v[i];
                e0[mt][i] = rowsum16(kk0 * q0);   // S[n, 2w]   (all 16 lanes)
                e1[mt][i] = rowsum16(kk1 * q1);   // S[n, 2w+1]
            }
        }
        // masked score + max
        float m0 = -3e38f, m1 = -3e38f;
        #pragma unroll
        for (int mt = 0; mt < 4; ++mt)
            #pragma unroll
            for (int i = 0; i < 4; ++i) {
                float ma = maskadd[mt*16 + g*4 + i];
                e0[mt][i] = fmaf(e0[mt][i], NORMS, ma);
                e1[mt][i] = fmaf(e1[mt][i], NORMS, ma);
                m0 = fmaxf(m0, e0[mt][i]);
                m1 = fmaxf(m1, e1[mt][i]);
            }
        m0 = fmaxf(m0, __shfl_xor(m0, 16));
        m0 = fmaxf(m0, __shfl_xor(m0, 32));
        m1 = fmaxf(m1, __shfl_xor(m1, 16));
        m1 = fmaxf(m1, __shfl_xor(m1, 32));
        // exp + sum
        float s0 = 0.f, s1 = 0.f;
        #pragma unroll
        for (int mt = 0; mt < 4; ++mt)
            #pragma unroll
            for (int i = 0; i < 4; ++i) {
                e0[mt][i] = __expf(e0[mt][i] - m0);
                e1[mt][i] = __expf(e1[mt][i] - m1);
                s0 += e0[mt][i];
                s1 += e1[mt][i];
            }
        s0 += __shfl_xor(s0, 16);  s0 += __shfl_xor(s0, 32);
        s1 += __shfl_xor(s1, 16);  s1 += __shfl_xor(s1, 32);
        float r0 = 1.f / s0, r1 = 1.f / s1;
        // write attn_t[n][2w + d] from lanes d<2 of each group
        #pragma unroll
        for (int mt = 0; mt < 4; ++mt)
            #pragma unroll
            for (int i = 0; i < 4; ++i) {
                float av = (d == 0) ? e0[mt][i] * r0 : e1[mt][i] * r1;
                if (d < 2)
                    attn_t[mt*16 + g*4 + i][2*w + d] = av;
            }
    } else {
        // ---- v path (waves 4-7): gather v rows + bias into acc (f32) ----
        const int cw = (w - 4) * 32;
        const float bv0 = bias_kv[HID + cw + d];
        const float bv1 = bias_kv[HID + cw + 16 + d];
        #pragma unroll
        for (int mt = 0; mt < 4; ++mt) {
            float v0v[4], v1v[4];
            #pragma unroll
            for (int i = 0; i < 4; ++i) {
                int n = mt*16 + g*4 + i;
                const float* trow = v_tab + (size_t)nb_lds[n]*HID + cw + d;
                v0v[i] = trow[0];
                v1v[i] = trow[16];
            }
            #pragma unroll
            for (int i = 0; i < 4; ++i) {
                acc[mt][0][i] += bv0 + v0v[i];
                acc[mt][1][i] += bv1 + v1v[i];
            }
        }
    }
    __syncthreads();   // barrier 2: attn_t ready

    // ---- phase 5: PV in registers (waves 4-7 hold v) + cross-group reduce ----
    if (w >= 4) {
        int gq = w - 4;
        float p[2] = {0.f, 0.f};
        #pragma unroll
        for (int mt = 0; mt < 4; ++mt) {
            #pragma unroll
            for (int i = 0; i < 4; ++i) {
                int n = mt*16 + g*4 + i;
                #pragma unroll
                for (int j = 0; j < 2; ++j)
                    p[j] = fmaf(attn_t[n][2*gq + j], acc[mt][j][i], p[j]);
            }
        }
        #pragma unroll
        for (int j = 0; j < 2; ++j) {
            p[j] += __shfl_xor(p[j], 16);
            p[j] += __shfl_xor(p[j], 32);
        }
        if (l < 16) {
            #pragma unroll
            for (int j = 0; j < 2; ++j) {
                int col = gq*32 + j*16 + l;
                out[(size_t)b*HID + col] = anyvalid ? p[j] : 0.f;
            }
        }
    }
}

extern "C" void kernel_launch(void* const* d_in, const int* in_sizes, int n_in,
                              void* d_out, int out_size, void* d_ws, size_t ws_size,
                              hipStream_t stream)
{
    const float* k_tab = (const float*)d_in[0];
    const float* q_tab = (const float*)d_in[1];
    const float* v_tab = (const float*)d_in[2];
    const int*   nid   = (const int*)d_in[3];
    const int*   neighbors = (const int*)d_in[4];
    const float* times = (const float*)d_in[5];
    const float* rels  = (const float*)d_in[6];
    const float* t2v_w = (const float*)d_in[7];
    const float* t2v_b = (const float*)d_in[8];
    const float* tW_k  = (const float*)d_in[9];
    const float* tb_k  = (const float*)d_in[10];
    const float* tW_q  = (const float*)d_in[11];
    const float* tb_q  = (const float*)d_in[12];
    const float* tW_v  = (const float*)d_in[13];
    const float* tb_v  = (const float*)d_in[14];
    const float* rW_k  = (const float*)d_in[15];
    const float* rb_k  = (const float*)d_in[16];
    const float* rW_v  = (const float*)d_in[17];
    const float* rb_v  = (const float*)d_in[18];

    short* wfrag   = (short*)d_ws;                          // 32768 bf16 = 64KB
    float* bias_kv = (float*)((char*)d_ws + 65536);         // 256 f32
    float* q0_add  = (float*)((char*)d_ws + 65536 + 1024);  // 128 f32

    prep_kernel<<<130, 256, 0, stream>>>(t2v_w, t2v_b, tW_k, tb_k, tW_q, tb_q,
                                         tW_v, tb_v, rW_k, rb_k, rW_v, rb_v,
                                         wfrag, bias_kv, q0_add);
    aggr_kernel<<<BATCH, 512, 0, stream>>>(k_tab, q_tab, v_tab, nid, neighbors,
                                           times, rels, t2v_w, t2v_b,
                                           wfrag, bias_kv, q0_add, (float*)d_out);
}

// Round 11
// 65.182 us; speedup vs baseline: 1.2715x; 1.0667x over previous
//
#include <hip/hip_runtime.h>
#include <hip/hip_bf16.h>

#define NUM_NODES 100000
#define BATCH 4096
#define NNB 64
#define HID 128
#define NHEAD 8
#define HDIM 16
#define TDIM 64
#define RDIM 64
#define START_TC 0.2f
#define END_TC 0.8f
#define NORMS 0.25f

typedef __attribute__((ext_vector_type(4))) float f32x4;
typedef __attribute__((ext_vector_type(2))) float f32x2;
typedef __attribute__((ext_vector_type(8))) short bf16x8;

#define AST 136   // A-tile row stride in shorts (272B: 16B-aligned rows)
#define KST 130   // K tile row stride in shorts (260B)
#define APAD 10   // attn_t row stride in floats (40B: 8B-aligned f32x2 reads, conflict-free)

__device__ __forceinline__ short fb(float f) {
    __hip_bfloat16 h = __float2bfloat16(f);   // RNE; hardware cvt on gfx950 if available
    return *reinterpret_cast<short*>(&h);
}

// Pack weights into MFMA B-fragment order, combined biases, and q0 = t_q(START_T).
__global__ void prep_kernel(const float* __restrict__ t2v_w, const float* __restrict__ t2v_b,
                            const float* __restrict__ tW_k, const float* __restrict__ tb_k,
                            const float* __restrict__ tW_q, const float* __restrict__ tb_q,
                            const float* __restrict__ tW_v, const float* __restrict__ tb_v,
                            const float* __restrict__ rW_k, const float* __restrict__ rb_k,
                            const float* __restrict__ rW_v, const float* __restrict__ rb_v,
                            short* __restrict__ wfrag, float* __restrict__ bias_kv,
                            float* __restrict__ q0_add)
{
    int blk = blockIdx.x, t = threadIdx.x;
    if (blk < 128) {
        int idx = blk * 256 + t;
        int i   = idx & 7;
        int ln  = (idx >> 3) & 63;
        int nt  = (idx >> 9) & 15;
        int kt  = idx >> 13;
        int k = kt * 32 + (ln >> 4) * 8 + i;
        int c = nt * 16 + (ln & 15);
        int cc = (c < HID) ? c : c - HID;
        float val;
        if (k < TDIM) val = (c < HID) ? tW_k[k*HID + cc] : tW_v[k*HID + cc];
        else          val = (c < HID) ? rW_k[(k-TDIM)*HID + cc] : rW_v[(k-TDIM)*HID + cc];
        wfrag[idx] = fb(val);
    } else if (blk == 128) {
        bias_kv[t] = (t < HID) ? (tb_k[t] + rb_k[t]) : (tb_v[t-HID] + rb_v[t-HID]);
    } else if (t < HID) {
        float s = tb_q[t];
        for (int j = 0; j < TDIM; ++j) {
            float f = START_TC * t2v_w[j] + t2v_b[j];
            float tv = (j == 0) ? f : __sinf(f);
            s += tv * tW_q[j*HID + t];
        }
        q0_add[t] = s;
    }
}

// 512 threads = 8 waves, R6 structure + B-fragment prefetch + batched gathers.
__launch_bounds__(512, 4)
__global__ void aggr_kernel(const float* __restrict__ k_tab, const float* __restrict__ q_tab,
                            const float* __restrict__ v_tab,
                            const int* __restrict__ nid, const int* __restrict__ neighbors,
                            const float* __restrict__ times, const float* __restrict__ rels,
                            const float* __restrict__ t2v_w, const float* __restrict__ t2v_b,
                            const short* __restrict__ wfrag, const float* __restrict__ bias_kv,
                            const float* __restrict__ q0_add, float* __restrict__ out)
{
    // A-tile (GEMM input) is dead after phase 2; Ksh reuses the same LDS.
    __shared__ __align__(16) short AK[64 * AST];
    __shared__ __align__(16) float q_lds[HID];
    __shared__ float maskadd[NNB];
    __shared__ int   nb_lds[NNB];
    __shared__ __align__(16) float attn_t[NNB][APAD];   // [n][head]
    __shared__ int   anyvalid;

    short* A   = AK;   // stride AST, phases 1-2
    short* Ksh = AK;   // stride KST, phases 3-4

    const int b = blockIdx.x;
    const int t = threadIdx.x;
    const int w = t >> 6;   // wave 0..7
    const int l = t & 63;   // lane

    // ---- prefetch: B-fragments for this wave's GEMM columns (no deps, L2-hot) ----
    const bf16x8* wf = (const bf16x8*)wfrag;
    bf16x8 bfr[4][2];
    #pragma unroll
    for (int kt = 0; kt < 4; ++kt)
        #pragma unroll
        for (int j = 0; j < 2; ++j)
            bfr[kt][j] = wf[(kt*16 + (2*w + j))*64 + l];

    // ---- phase 0: neighbors / mask / q (consumers all after first barrier) ----
    if (t < 64) {
        nb_lds[t] = neighbors[b*NNB + t];
        float tt = times[b*NNB + t];
        bool valid = (tt >= START_TC) && (tt < END_TC);
        maskadd[t] = valid ? 0.f : -1e30f;
        unsigned long long bal = __ballot(valid);
        if (t == 0) anyvalid = (bal != 0ull) ? 1 : 0;
    } else if (t < 96) {
        int i = t - 64;                 // 0..31
        int q_node = nid[b];
        f32x4 qa = *(const f32x4*)(q_tab + (size_t)q_node*HID + i*4);
        f32x4 qb = *(const f32x4*)(q0_add + i*4);
        *(f32x4*)(q_lds + i*4) = qa + qb;
    }

    // ---- phase 1: stage A-tile = [t2v(times) | rels], wave-specialized ----
    if (w < 4) {
        float tt = times[b*NNB + l];
        int c0 = w * 16;
        bf16x8 v0, v1;
        #pragma unroll
        for (int u = 0; u < 8; ++u) {
            int j = c0 + u;
            float f = fmaf(tt, t2v_w[j], t2v_b[j]);
            v0[u] = fb((j == 0) ? f : __sinf(f));
        }
        #pragma unroll
        for (int u = 0; u < 8; ++u) {
            int j = c0 + 8 + u;
            float f = fmaf(tt, t2v_w[j], t2v_b[j]);
            v1[u] = fb(__sinf(f));
        }
        *(bf16x8*)(&A[l*AST + c0])     = v0;
        *(bf16x8*)(&A[l*AST + c0 + 8]) = v1;
    } else {
        int s = w - 4;
        const float* rp = rels + ((size_t)b*NNB + l)*RDIM + s*16;
        f32x4 r0 = *(const f32x4*)(rp);
        f32x4 r1 = *(const f32x4*)(rp + 4);
        f32x4 r2 = *(const f32x4*)(rp + 8);
        f32x4 r3 = *(const f32x4*)(rp + 12);
        bf16x8 o0, o1;
        #pragma unroll
        for (int e = 0; e < 4; ++e) {
            o0[e]   = fb(r0[e]);  o0[e+4] = fb(r1[e]);
            o1[e]   = fb(r2[e]);  o1[e+4] = fb(r3[e]);
        }
        *(bf16x8*)(&A[l*AST + TDIM + s*16])     = o0;
        *(bf16x8*)(&A[l*AST + TDIM + s*16 + 8]) = o1;
    }
    __syncthreads();

    // ---- phase 2: GEMM [64x128] @ [128x256]; wave w owns cols 32w..32w+31 ----
    f32x4 acc[4][2];
    #pragma unroll
    for (int mt = 0; mt < 4; ++mt)
        #pragma unroll
        for (int j = 0; j < 2; ++j)
            acc[mt][j] = (f32x4){0.f, 0.f, 0.f, 0.f};

    #pragma unroll
    for (int kt = 0; kt < 4; ++kt) {
        bf16x8 af[4];
        int kcol = kt*32 + (l >> 4)*8;
        #pragma unroll
        for (int mt = 0; mt < 4; ++mt)
            af[mt] = *(const bf16x8*)(&A[(mt*16 + (l & 15))*AST + kcol]);
        #pragma unroll
        for (int mt = 0; mt < 4; ++mt)
            #pragma unroll
            for (int j = 0; j < 2; ++j)
                acc[mt][j] = __builtin_amdgcn_mfma_f32_16x16x32_bf16(af[mt], bfr[kt][j], acc[mt][j], 0, 0, 0);
    }
    __syncthreads();   // A is dead; Ksh may now overwrite it

    // ---- phase 3: gather table rows (batched, branch-free) + bias ----
    if (w < 4) {
        int cw = w * 32;
        float biasr[2];
        #pragma unroll
        for (int j = 0; j < 2; ++j)
            biasr[j] = bias_kv[cw + j*16 + (l & 15)];
        #pragma unroll
        for (int mt = 0; mt < 4; ++mt) {
            float k0v[4], k1v[4];
            #pragma unroll
            for (int i = 0; i < 4; ++i) {
                int n = mt*16 + ((l >> 4) << 2) + i;
                const float* trow = k_tab + (size_t)nb_lds[n]*HID + cw + (l & 15);
                k0v[i] = trow[0];
                k1v[i] = trow[16];
            }
            #pragma unroll
            for (int i = 0; i < 4; ++i) {
                int n = mt*16 + ((l >> 4) << 2) + i;
                Ksh[n*KST + cw +      (l & 15)] = fb(acc[mt][0][i] + biasr[0] + k0v[i]);
                Ksh[n*KST + cw + 16 + (l & 15)] = fb(acc[mt][1][i] + biasr[1] + k1v[i]);
            }
        }
    } else {
        int cw = (w - 4) * 32;
        float biasr[2];
        #pragma unroll
        for (int j = 0; j < 2; ++j)
            biasr[j] = bias_kv[HID + cw + j*16 + (l & 15)];
        #pragma unroll
        for (int mt = 0; mt < 4; ++mt) {
            float v0v[4], v1v[4];
            #pragma unroll
            for (int i = 0; i < 4; ++i) {
                int n = mt*16 + ((l >> 4) << 2) + i;
                const float* trow = v_tab + (size_t)nb_lds[n]*HID + cw + (l & 15);
                v0v[i] = trow[0];
                v1v[i] = trow[16];
            }
            #pragma unroll
            for (int i = 0; i < 4; ++i) {
                acc[mt][0][i] += biasr[0] + v0v[i];
                acc[mt][1][i] += biasr[1] + v1v[i];
            }
        }
    }
    __syncthreads();

    // ---- phase 4: scores + softmax. lane l = neighbor l; wave w = head w ----
    {
        const short* krow = &Ksh[l*KST + w*16];
        float s = 0.f;
        #pragma unroll
        for (int e = 0; e < 8; ++e) {
            unsigned u = *(const unsigned*)(&krow[2*e]);
            float k0 = __uint_as_float(u << 16);
            float k1 = __uint_as_float(u & 0xffff0000u);
            s = fmaf(q_lds[w*16 + 2*e],     k0, s);
            s = fmaf(q_lds[w*16 + 2*e + 1], k1, s);
        }
        float sc = s * NORMS + maskadd[l];
        float m = sc;
        #pragma unroll
        for (int off = 1; off <= 32; off <<= 1)
            m = fmaxf(m, __shfl_xor(m, off));
        float e = __expf(sc - m);
        float sum = e;
        #pragma unroll
        for (int off = 1; off <= 32; off <<= 1)
            sum += __shfl_xor(sum, off);
        attn_t[l][w] = e / sum;
    }
    __syncthreads();

    // ---- phase 5: PV in registers (waves 4-7 hold v) + cross-group reduce ----
    if (w >= 4) {
        int g = w - 4;
        float p[2] = {0.f, 0.f};
        #pragma unroll
        for (int mt = 0; mt < 4; ++mt) {
            #pragma unroll
            for (int i = 0; i < 4; ++i) {
                int n = mt*16 + ((l >> 4) << 2) + i;
                f32x2 at = *(const f32x2*)(&attn_t[n][2*g]);
                p[0] = fmaf(at[0], acc[mt][0][i], p[0]);
                p[1] = fmaf(at[1], acc[mt][1][i], p[1]);
            }
        }
        #pragma unroll
        for (int j = 0; j < 2; ++j) {
            p[j] += __shfl_xor(p[j], 16);
            p[j] += __shfl_xor(p[j], 32);
        }
        if (l < 16) {
            #pragma unroll
            for (int j = 0; j < 2; ++j) {
                int col = g*32 + j*16 + l;
                out[(size_t)b*HID + col] = anyvalid ? p[j] : 0.f;
            }
        }
    }
}

extern "C" void kernel_launch(void* const* d_in, const int* in_sizes, int n_in,
                              void* d_out, int out_size, void* d_ws, size_t ws_size,
                              hipStream_t stream)
{
    const float* k_tab = (const float*)d_in[0];
    const float* q_tab = (const float*)d_in[1];
    const float* v_tab = (const float*)d_in[2];
    const int*   nid   = (const int*)d_in[3];
    const int*   neighbors = (const int*)d_in[4];
    const float* times = (const float*)d_in[5];
    const float* rels  = (const float*)d_in[6];
    const float* t2v_w = (const float*)d_in[7];
    const float* t2v_b = (const float*)d_in[8];
    const float* tW_k  = (const float*)d_in[9];
    const float* tb_k  = (const float*)d_in[10];
    const float* tW_q  = (const float*)d_in[11];
    const float* tb_q  = (const float*)d_in[12];
    const float* tW_v  = (const float*)d_in[13];
    const float* tb_v  = (const float*)d_in[14];
    const float* rW_k  = (const float*)d_in[15];
    const float* rb_k  = (const float*)d_in[16];
    const float* rW_v  = (const float*)d_in[17];
    const float* rb_v  = (const float*)d_in[18];

    short* wfrag   = (short*)d_ws;                          // 32768 bf16 = 64KB
    float* bias_kv = (float*)((char*)d_ws + 65536);         // 256 f32
    float* q0_add  = (float*)((char*)d_ws + 65536 + 1024);  // 128 f32

    prep_kernel<<<130, 256, 0, stream>>>(t2v_w, t2v_b, tW_k, tb_k, tW_q, tb_q,
                                         tW_v, tb_v, rW_k, rb_k, rW_v, rb_v,
                                         wfrag, bias_kv, q0_add);
    aggr_kernel<<<BATCH, 512, 0, stream>>>(k_tab, q_tab, v_tab, nid, neighbors,
                                           times, rels, t2v_w, t2v_b,
                                           wfrag, bias_kv, q0_add, (float*)d_out);
}

// Round 12
// 50.581 us; speedup vs baseline: 1.6386x; 1.2887x over previous
//
#include <hip/hip_runtime.h>
#include <hip/hip_bf16.h>

#define NUM_NODES 100000
#define BATCH 4096
#define NNB 64
#define HID 128
#define NHEAD 8
#define HDIM 16
#define TDIM 64
#define RDIM 64
#define START_TC 0.2f
#define END_TC 0.8f
#define NORMS 0.25f

typedef __attribute__((ext_vector_type(4))) float f32x4;
typedef __attribute__((ext_vector_type(2))) float f32x2;
typedef __attribute__((ext_vector_type(8))) short bf16x8;

#define AST 136   // A-tile row stride in shorts (272B: 16B-aligned rows)
#define KST 130   // K tile row stride in shorts (260B)
#define APAD 10   // attn_t row stride in floats (40B: 8B-aligned f32x2 reads)

__device__ __forceinline__ short fb(float f) {
    __hip_bfloat16 h = __float2bfloat16(f);
    return *reinterpret_cast<short*>(&h);
}

// Pack weights into MFMA B-fragment order, combined biases, and q0 = t_q(START_T).
__global__ void prep_kernel(const float* __restrict__ t2v_w, const float* __restrict__ t2v_b,
                            const float* __restrict__ tW_k, const float* __restrict__ tb_k,
                            const float* __restrict__ tW_q, const float* __restrict__ tb_q,
                            const float* __restrict__ tW_v, const float* __restrict__ tb_v,
                            const float* __restrict__ rW_k, const float* __restrict__ rb_k,
                            const float* __restrict__ rW_v, const float* __restrict__ rb_v,
                            short* __restrict__ wfrag, float* __restrict__ bias_kv,
                            float* __restrict__ q0_add)
{
    int blk = blockIdx.x, t = threadIdx.x;
    if (blk < 128) {
        int idx = blk * 256 + t;
        int i   = idx & 7;
        int ln  = (idx >> 3) & 63;
        int nt  = (idx >> 9) & 15;
        int kt  = idx >> 13;
        int k = kt * 32 + (ln >> 4) * 8 + i;
        int c = nt * 16 + (ln & 15);
        int cc = (c < HID) ? c : c - HID;
        float val;
        if (k < TDIM) val = (c < HID) ? tW_k[k*HID + cc] : tW_v[k*HID + cc];
        else          val = (c < HID) ? rW_k[(k-TDIM)*HID + cc] : rW_v[(k-TDIM)*HID + cc];
        wfrag[idx] = fb(val);
    } else if (blk == 128) {
        bias_kv[t] = (t < HID) ? (tb_k[t] + rb_k[t]) : (tb_v[t-HID] + rb_v[t-HID]);
    } else if (t < HID) {
        float s = tb_q[t];
        for (int j = 0; j < TDIM; ++j) {
            float f = START_TC * t2v_w[j] + t2v_b[j];
            float tv = (j == 0) ? f : __sinf(f);
            s += tv * tW_q[j*HID + t];
        }
        q0_add[t] = s;
    }
}

// 512 threads = 8 waves. R6 structure + B-frag prefetch + PREDICATED gather:
// validity is uniform per 16-lane group (n independent of lane-within-16), so
// masked groups redirect to table row 0 (one hot L2 line) -- loads stay
// batched/coalesced, ~40% of gather bytes vanish from the L2/L3 path.
__launch_bounds__(512, 6)
__global__ void aggr_kernel(const float* __restrict__ k_tab, const float* __restrict__ q_tab,
                            const float* __restrict__ v_tab,
                            const int* __restrict__ nid, const int* __restrict__ neighbors,
                            const float* __restrict__ times, const float* __restrict__ rels,
                            const float* __restrict__ t2v_w, const float* __restrict__ t2v_b,
                            const short* __restrict__ wfrag, const float* __restrict__ bias_kv,
                            const float* __restrict__ q0_add, float* __restrict__ out)
{
    __shared__ __align__(16) short AK[64 * AST];
    __shared__ __align__(16) float q_lds[HID];
    __shared__ float maskadd[NNB];
    __shared__ int   nb_lds[NNB];     // masked entries forced to 0 (dummy row)
    __shared__ __align__(16) float attn_t[NNB][APAD];
    __shared__ int   anyvalid;

    short* A   = AK;   // stride AST, phases 1-2
    short* Ksh = AK;   // stride KST, phases 3-4

    const int b = blockIdx.x;
    const int t = threadIdx.x;
    const int w = t >> 6;   // wave 0..7
    const int l = t & 63;   // lane

    // ---- prefetch: B-fragments for this wave's GEMM columns ----
    const bf16x8* wf = (const bf16x8*)wfrag;
    bf16x8 bfr[4][2];
    #pragma unroll
    for (int kt = 0; kt < 4; ++kt)
        #pragma unroll
        for (int j = 0; j < 2; ++j)
            bfr[kt][j] = wf[(kt*16 + (2*w + j))*64 + l];

    // ---- phase 0: neighbors / mask / q ----
    if (t < 64) {
        float tt = times[b*NNB + t];
        bool valid = (tt >= START_TC) && (tt < END_TC);
        // predication at the source: masked neighbors gather table row 0
        nb_lds[t] = valid ? neighbors[b*NNB + t] : 0;
        maskadd[t] = valid ? 0.f : -1e30f;
        unsigned long long bal = __ballot(valid);
        if (t == 0) anyvalid = (bal != 0ull) ? 1 : 0;
    } else if (t < 96) {
        int i = t - 64;
        int q_node = nid[b];
        f32x4 qa = *(const f32x4*)(q_tab + (size_t)q_node*HID + i*4);
        f32x4 qb = *(const f32x4*)(q0_add + i*4);
        *(f32x4*)(q_lds + i*4) = qa + qb;
    }

    // ---- phase 1: stage A-tile = [t2v(times) | rels], wave-specialized ----
    if (w < 4) {
        float tt = times[b*NNB + l];
        int c0 = w * 16;
        bf16x8 v0, v1;
        #pragma unroll
        for (int u = 0; u < 8; ++u) {
            int j = c0 + u;
            float f = fmaf(tt, t2v_w[j], t2v_b[j]);
            v0[u] = fb((j == 0) ? f : __sinf(f));
        }
        #pragma unroll
        for (int u = 0; u < 8; ++u) {
            int j = c0 + 8 + u;
            float f = fmaf(tt, t2v_w[j], t2v_b[j]);
            v1[u] = fb(__sinf(f));
        }
        *(bf16x8*)(&A[l*AST + c0])     = v0;
        *(bf16x8*)(&A[l*AST + c0 + 8]) = v1;
    } else {
        int s = w - 4;
        const float* rp = rels + ((size_t)b*NNB + l)*RDIM + s*16;
        f32x4 r0 = *(const f32x4*)(rp);
        f32x4 r1 = *(const f32x4*)(rp + 4);
        f32x4 r2 = *(const f32x4*)(rp + 8);
        f32x4 r3 = *(const f32x4*)(rp + 12);
        bf16x8 o0, o1;
        #pragma unroll
        for (int e = 0; e < 4; ++e) {
            o0[e]   = fb(r0[e]);  o0[e+4] = fb(r1[e]);
            o1[e]   = fb(r2[e]);  o1[e+4] = fb(r3[e]);
        }
        *(bf16x8*)(&A[l*AST + TDIM + s*16])     = o0;
        *(bf16x8*)(&A[l*AST + TDIM + s*16 + 8]) = o1;
    }
    __syncthreads();

    // ---- phase 2: GEMM [64x128] @ [128x256]; wave w owns cols 32w..32w+31 ----
    f32x4 acc[4][2];
    #pragma unroll
    for (int mt = 0; mt < 4; ++mt)
        #pragma unroll
        for (int j = 0; j < 2; ++j)
            acc[mt][j] = (f32x4){0.f, 0.f, 0.f, 0.f};

    #pragma unroll
    for (int kt = 0; kt < 4; ++kt) {
        bf16x8 af[4];
        int kcol = kt*32 + (l >> 4)*8;
        #pragma unroll
        for (int mt = 0; mt < 4; ++mt)
            af[mt] = *(const bf16x8*)(&A[(mt*16 + (l & 15))*AST + kcol]);
        #pragma unroll
        for (int mt = 0; mt < 4; ++mt)
            #pragma unroll
            for (int j = 0; j < 2; ++j)
                acc[mt][j] = __builtin_amdgcn_mfma_f32_16x16x32_bf16(af[mt], bfr[kt][j], acc[mt][j], 0, 0, 0);
    }
    __syncthreads();   // A dead; Ksh may overwrite

    // ---- phase 3: gather table rows (batched, branch-free, dummy-predicated) ----
    // Masked n -> nb_lds[n]==0 -> all masked groups hit the same hot row-0 lines.
    // Garbage values flow into Ksh/acc for masked n but are annihilated by the
    // -1e30 mask (exp -> exactly 0) resp. x0 attention weight in PV.
    if (w < 4) {
        int cw = w * 32;
        float biasr[2];
        #pragma unroll
        for (int j = 0; j < 2; ++j)
            biasr[j] = bias_kv[cw + j*16 + (l & 15)];
        #pragma unroll
        for (int mt = 0; mt < 4; ++mt) {
            float k0v[4], k1v[4];
            #pragma unroll
            for (int i = 0; i < 4; ++i) {
                int n = mt*16 + ((l >> 4) << 2) + i;
                const float* trow = k_tab + (size_t)nb_lds[n]*HID + cw + (l & 15);
                k0v[i] = trow[0];
                k1v[i] = trow[16];
            }
            #pragma unroll
            for (int i = 0; i < 4; ++i) {
                int n = mt*16 + ((l >> 4) << 2) + i;
                Ksh[n*KST + cw +      (l & 15)] = fb(acc[mt][0][i] + biasr[0] + k0v[i]);
                Ksh[n*KST + cw + 16 + (l & 15)] = fb(acc[mt][1][i] + biasr[1] + k1v[i]);
            }
        }
    } else {
        int cw = (w - 4) * 32;
        float biasr[2];
        #pragma unroll
        for (int j = 0; j < 2; ++j)
            biasr[j] = bias_kv[HID + cw + j*16 + (l & 15)];
        #pragma unroll
        for (int mt = 0; mt < 4; ++mt) {
            float v0v[4], v1v[4];
            #pragma unroll
            for (int i = 0; i < 4; ++i) {
                int n = mt*16 + ((l >> 4) << 2) + i;
                const float* trow = v_tab + (size_t)nb_lds[n]*HID + cw + (l & 15);
                v0v[i] = trow[0];
                v1v[i] = trow[16];
            }
            #pragma unroll
            for (int i = 0; i < 4; ++i) {
                acc[mt][0][i] += biasr[0] + v0v[i];
                acc[mt][1][i] += biasr[1] + v1v[i];
            }
        }
    }
    __syncthreads();

    // ---- phase 4: scores + softmax. lane l = neighbor l; wave w = head w ----
    {
        const short* krow = &Ksh[l*KST + w*16];
        float s = 0.f;
        #pragma unroll
        for (int e = 0; e < 8; ++e) {
            unsigned u = *(const unsigned*)(&krow[2*e]);
            float k0 = __uint_as_float(u << 16);
            float k1 = __uint_as_float(u & 0xffff0000u);
            s = fmaf(q_lds[w*16 + 2*e],     k0, s);
            s = fmaf(q_lds[w*16 + 2*e + 1], k1, s);
        }
        float sc = s * NORMS + maskadd[l];
        float m = sc;
        #pragma unroll
        for (int off = 1; off <= 32; off <<= 1)
            m = fmaxf(m, __shfl_xor(m, off));
        float e = __expf(sc - m);
        float sum = e;
        #pragma unroll
        for (int off = 1; off <= 32; off <<= 1)
            sum += __shfl_xor(sum, off);
        attn_t[l][w] = e / sum;
    }
    __syncthreads();

    // ---- phase 5: PV in registers (waves 4-7 hold v) + cross-group reduce ----
    if (w >= 4) {
        int g = w - 4;
        float p[2] = {0.f, 0.f};
        #pragma unroll
        for (int mt = 0; mt < 4; ++mt) {
            #pragma unroll
            for (int i = 0; i < 4; ++i) {
                int n = mt*16 + ((l >> 4) << 2) + i;
                f32x2 at = *(const f32x2*)(&attn_t[n][2*g]);
                p[0] = fmaf(at[0], acc[mt][0][i], p[0]);
                p[1] = fmaf(at[1], acc[mt][1][i], p[1]);
            }
        }
        #pragma unroll
        for (int j = 0; j < 2; ++j) {
            p[j] += __shfl_xor(p[j], 16);
            p[j] += __shfl_xor(p[j], 32);
        }
        if (l < 16) {
            #pragma unroll
            for (int j = 0; j < 2; ++j) {
                int col = g*32 + j*16 + l;
                out[(size_t)b*HID + col] = anyvalid ? p[j] : 0.f;
            }
        }
    }
}

extern "C" void kernel_launch(void* const* d_in, const int* in_sizes, int n_in,
                              void* d_out, int out_size, void* d_ws, size_t ws_size,
                              hipStream_t stream)
{
    const float* k_tab = (const float*)d_in[0];
    const float* q_tab = (const float*)d_in[1];
    const float* v_tab = (const float*)d_in[2];
    const int*   nid   = (const int*)d_in[3];
    const int*   neighbors = (const int*)d_in[4];
    const float* times = (const float*)d_in[5];
    const float* rels  = (const float*)d_in[6];
    const float* t2v_w = (const float*)d_in[7];
    const float* t2v_b = (const float*)d_in[8];
    const float* tW_k  = (const float*)d_in[9];
    const float* tb_k  = (const float*)d_in[10];
    const float* tW_q  = (const float*)d_in[11];
    const float* tb_q  = (const float*)d_in[12];
    const float* tW_v  = (const float*)d_in[13];
    const float* tb_v  = (const float*)d_in[14];
    const float* rW_k  = (const float*)d_in[15];
    const float* rb_k  = (const float*)d_in[16];
    const float* rW_v  = (const float*)d_in[17];
    const float* rb_v  = (const float*)d_in[18];

    short* wfrag   = (short*)d_ws;                          // 32768 bf16 = 64KB
    float* bias_kv = (float*)((char*)d_ws + 65536);         // 256 f32
    float* q0_add  = (float*)((char*)d_ws + 65536 + 1024);  // 128 f32

    prep_kernel<<<130, 256, 0, stream>>>(t2v_w, t2v_b, tW_k, tb_k, tW_q, tb_q,
                                         tW_v, tb_v, rW_k, rb_k, rW_v, rb_v,
                                         wfrag, bias_kv, q0_add);
    aggr_kernel<<<BATCH, 512, 0, stream>>>(k_tab, q_tab, v_tab, nid, neighbors,
                                           times, rels, t2v_w, t2v_b,
                                           wfrag, bias_kv, q0_add, (float*)d_out);
}

// Round 13
// 50.106 us; speedup vs baseline: 1.6541x; 1.0095x over previous
//
#include <hip/hip_runtime.h>
#include <hip/hip_bf16.h>

#define NUM_NODES 100000
#define BATCH 4096
#define NNB 64
#define HID 128
#define NHEAD 8
#define HDIM 16
#define TDIM 64
#define RDIM 64
#define START_TC 0.2f
#define END_TC 0.8f
#define NORMS 0.25f

typedef __attribute__((ext_vector_type(4))) float f32x4;
typedef __attribute__((ext_vector_type(2))) float f32x2;
typedef __attribute__((ext_vector_type(8))) short bf16x8;

#define AST 136   // A-tile row stride in shorts (272B: 16B-aligned rows)
#define KST 130   // K tile row stride in shorts (260B)
#define APAD 10   // attn_t row stride in floats (40B: 8B-aligned f32x2 reads)

__device__ __forceinline__ short fb(float f) {
    __hip_bfloat16 h = __float2bfloat16(f);
    return *reinterpret_cast<short*>(&h);
}

// Pack weights into MFMA B-fragment order, combined biases, and q0 = t_q(START_T).
__global__ void prep_kernel(const float* __restrict__ t2v_w, const float* __restrict__ t2v_b,
                            const float* __restrict__ tW_k, const float* __restrict__ tb_k,
                            const float* __restrict__ tW_q, const float* __restrict__ tb_q,
                            const float* __restrict__ tW_v, const float* __restrict__ tb_v,
                            const float* __restrict__ rW_k, const float* __restrict__ rb_k,
                            const float* __restrict__ rW_v, const float* __restrict__ rb_v,
                            short* __restrict__ wfrag, float* __restrict__ bias_kv,
                            float* __restrict__ q0_add)
{
    int blk = blockIdx.x, t = threadIdx.x;
    if (blk < 128) {
        int idx = blk * 256 + t;
        int i   = idx & 7;
        int ln  = (idx >> 3) & 63;
        int nt  = (idx >> 9) & 15;
        int kt  = idx >> 13;
        int k = kt * 32 + (ln >> 4) * 8 + i;
        int c = nt * 16 + (ln & 15);
        int cc = (c < HID) ? c : c - HID;
        float val;
        if (k < TDIM) val = (c < HID) ? tW_k[k*HID + cc] : tW_v[k*HID + cc];
        else          val = (c < HID) ? rW_k[(k-TDIM)*HID + cc] : rW_v[(k-TDIM)*HID + cc];
        wfrag[idx] = fb(val);
    } else if (blk == 128) {
        bias_kv[t] = (t < HID) ? (tb_k[t] + rb_k[t]) : (tb_v[t-HID] + rb_v[t-HID]);
    } else if (t < HID) {
        float s = tb_q[t];
        for (int j = 0; j < TDIM; ++j) {
            float f = START_TC * t2v_w[j] + t2v_b[j];
            float tv = (j == 0) ? f : __sinf(f);
            s += tv * tW_q[j*HID + t];
        }
        q0_add[t] = s;
    }
}

// 512 threads = 8 waves. R12 structure + predicated rels stream:
// masked rows (~40%) redirect BOTH their k/v gather (R12) and their rels
// stream (new) to hot dummy lines -- loads stay batched/coalesced, bytes
// vanish from the L2/L3 path. Masked garbage is annihilated by -1e30 mask
// (exp -> exactly 0) resp. x0 attention weight.
__launch_bounds__(512, 6)
__global__ void aggr_kernel(const float* __restrict__ k_tab, const float* __restrict__ q_tab,
                            const float* __restrict__ v_tab,
                            const int* __restrict__ nid, const int* __restrict__ neighbors,
                            const float* __restrict__ times, const float* __restrict__ rels,
                            const float* __restrict__ t2v_w, const float* __restrict__ t2v_b,
                            const short* __restrict__ wfrag, const float* __restrict__ bias_kv,
                            const float* __restrict__ q0_add, float* __restrict__ out)
{
    __shared__ __align__(16) short AK[64 * AST];
    __shared__ __align__(16) float q_lds[HID];
    __shared__ float maskadd[NNB];
    __shared__ int   nb_lds[NNB];     // masked entries forced to 0 (dummy row)
    __shared__ __align__(16) float attn_t[NNB][APAD];
    __shared__ int   anyvalid;

    short* A   = AK;   // stride AST, phases 1-2
    short* Ksh = AK;   // stride KST, phases 3-4

    const int b = blockIdx.x;
    const int t = threadIdx.x;
    const int w = t >> 6;   // wave 0..7
    const int l = t & 63;   // lane

    // ---- prefetch: B-fragments for this wave's GEMM columns ----
    const bf16x8* wf = (const bf16x8*)wfrag;
    bf16x8 bfr[4][2];
    #pragma unroll
    for (int kt = 0; kt < 4; ++kt)
        #pragma unroll
        for (int j = 0; j < 2; ++j)
            bfr[kt][j] = wf[(kt*16 + (2*w + j))*64 + l];

    // ---- phase 0: neighbors / mask / q ----
    if (t < 64) {
        float tt = times[b*NNB + t];
        bool valid = (tt >= START_TC) && (tt < END_TC);
        // predication at the source: masked neighbors gather table row 0
        nb_lds[t] = valid ? neighbors[b*NNB + t] : 0;
        maskadd[t] = valid ? 0.f : -1e30f;
        unsigned long long bal = __ballot(valid);
        if (t == 0) anyvalid = (bal != 0ull) ? 1 : 0;
    } else if (t < 96) {
        int i = t - 64;
        int q_node = nid[b];
        f32x4 qa = *(const f32x4*)(q_tab + (size_t)q_node*HID + i*4);
        f32x4 qb = *(const f32x4*)(q0_add + i*4);
        *(f32x4*)(q_lds + i*4) = qa + qb;
    }

    // ---- phase 1: stage A-tile = [t2v(times) | rels], wave-specialized ----
    if (w < 4) {
        float tt = times[b*NNB + l];
        int c0 = w * 16;
        bf16x8 v0, v1;
        #pragma unroll
        for (int u = 0; u < 8; ++u) {
            int j = c0 + u;
            float f = fmaf(tt, t2v_w[j], t2v_b[j]);
            v0[u] = fb((j == 0) ? f : __sinf(f));
        }
        #pragma unroll
        for (int u = 0; u < 8; ++u) {
            int j = c0 + 8 + u;
            float f = fmaf(tt, t2v_w[j], t2v_b[j]);
            v1[u] = fb(__sinf(f));
        }
        *(bf16x8*)(&A[l*AST + c0])     = v0;
        *(bf16x8*)(&A[l*AST + c0 + 8]) = v1;
    } else {
        int s = w - 4;
        // predicated rels stream: masked rows read the block's row-0 line (hot)
        float tt = times[b*NNB + l];
        bool valid = (tt >= START_TC) && (tt < END_TC);
        int lrow = valid ? l : 0;
        const float* rp = rels + ((size_t)b*NNB + lrow)*RDIM + s*16;
        f32x4 r0 = *(const f32x4*)(rp);
        f32x4 r1 = *(const f32x4*)(rp + 4);
        f32x4 r2 = *(const f32x4*)(rp + 8);
        f32x4 r3 = *(const f32x4*)(rp + 12);
        bf16x8 o0, o1;
        #pragma unroll
        for (int e = 0; e < 4; ++e) {
            o0[e]   = fb(r0[e]);  o0[e+4] = fb(r1[e]);
            o1[e]   = fb(r2[e]);  o1[e+4] = fb(r3[e]);
        }
        *(bf16x8*)(&A[l*AST + TDIM + s*16])     = o0;
        *(bf16x8*)(&A[l*AST + TDIM + s*16 + 8]) = o1;
    }
    __syncthreads();

    // ---- phase 2: GEMM [64x128] @ [128x256]; wave w owns cols 32w..32w+31 ----
    f32x4 acc[4][2];
    #pragma unroll
    for (int mt = 0; mt < 4; ++mt)
        #pragma unroll
        for (int j = 0; j < 2; ++j)
            acc[mt][j] = (f32x4){0.f, 0.f, 0.f, 0.f};

    #pragma unroll
    for (int kt = 0; kt < 4; ++kt) {
        bf16x8 af[4];
        int kcol = kt*32 + (l >> 4)*8;
        #pragma unroll
        for (int mt = 0; mt < 4; ++mt)
            af[mt] = *(const bf16x8*)(&A[(mt*16 + (l & 15))*AST + kcol]);
        #pragma unroll
        for (int mt = 0; mt < 4; ++mt)
            #pragma unroll
            for (int j = 0; j < 2; ++j)
                acc[mt][j] = __builtin_amdgcn_mfma_f32_16x16x32_bf16(af[mt], bfr[kt][j], acc[mt][j], 0, 0, 0);
    }
    __syncthreads();   // A dead; Ksh may overwrite

    // ---- phase 3: gather table rows (batched, branch-free, dummy-predicated) ----
    if (w < 4) {
        int cw = w * 32;
        float biasr[2];
        #pragma unroll
        for (int j = 0; j < 2; ++j)
            biasr[j] = bias_kv[cw + j*16 + (l & 15)];
        #pragma unroll
        for (int mt = 0; mt < 4; ++mt) {
            float k0v[4], k1v[4];
            #pragma unroll
            for (int i = 0; i < 4; ++i) {
                int n = mt*16 + ((l >> 4) << 2) + i;
                const float* trow = k_tab + (size_t)nb_lds[n]*HID + cw + (l & 15);
                k0v[i] = trow[0];
                k1v[i] = trow[16];
            }
            #pragma unroll
            for (int i = 0; i < 4; ++i) {
                int n = mt*16 + ((l >> 4) << 2) + i;
                Ksh[n*KST + cw +      (l & 15)] = fb(acc[mt][0][i] + biasr[0] + k0v[i]);
                Ksh[n*KST + cw + 16 + (l & 15)] = fb(acc[mt][1][i] + biasr[1] + k1v[i]);
            }
        }
    } else {
        int cw = (w - 4) * 32;
        float biasr[2];
        #pragma unroll
        for (int j = 0; j < 2; ++j)
            biasr[j] = bias_kv[HID + cw + j*16 + (l & 15)];
        #pragma unroll
        for (int mt = 0; mt < 4; ++mt) {
            float v0v[4], v1v[4];
            #pragma unroll
            for (int i = 0; i < 4; ++i) {
                int n = mt*16 + ((l >> 4) << 2) + i;
                const float* trow = v_tab + (size_t)nb_lds[n]*HID + cw + (l & 15);
                v0v[i] = trow[0];
                v1v[i] = trow[16];
            }
            #pragma unroll
            for (int i = 0; i < 4; ++i) {
                acc[mt][0][i] += biasr[0] + v0v[i];
                acc[mt][1][i] += biasr[1] + v1v[i];
            }
        }
    }
    __syncthreads();

    // ---- phase 4: scores + softmax. lane l = neighbor l; wave w = head w ----
    {
        const short* krow = &Ksh[l*KST + w*16];
        float s = 0.f;
        #pragma unroll
        for (int e = 0; e < 8; ++e) {
            unsigned u = *(const unsigned*)(&krow[2*e]);
            float k0 = __uint_as_float(u << 16);
            float k1 = __uint_as_float(u & 0xffff0000u);
            s = fmaf(q_lds[w*16 + 2*e],     k0, s);
            s = fmaf(q_lds[w*16 + 2*e + 1], k1, s);
        }
        float sc = s * NORMS + maskadd[l];
        float m = sc;
        #pragma unroll
        for (int off = 1; off <= 32; off <<= 1)
            m = fmaxf(m, __shfl_xor(m, off));
        float e = __expf(sc - m);
        float sum = e;
        #pragma unroll
        for (int off = 1; off <= 32; off <<= 1)
            sum += __shfl_xor(sum, off);
        attn_t[l][w] = e / sum;
    }
    __syncthreads();

    // ---- phase 5: PV in registers (waves 4-7 hold v) + cross-group reduce ----
    if (w >= 4) {
        int g = w - 4;
        float p[2] = {0.f, 0.f};
        #pragma unroll
        for (int mt = 0; mt < 4; ++mt) {
            #pragma unroll
            for (int i = 0; i < 4; ++i) {
                int n = mt*16 + ((l >> 4) << 2) + i;
                f32x2 at = *(const f32x2*)(&attn_t[n][2*g]);
                p[0] = fmaf(at[0], acc[mt][0][i], p[0]);
                p[1] = fmaf(at[1], acc[mt][1][i], p[1]);
            }
        }
        #pragma unroll
        for (int j = 0; j < 2; ++j) {
            p[j] += __shfl_xor(p[j], 16);
            p[j] += __shfl_xor(p[j], 32);
        }
        if (l < 16) {
            #pragma unroll
            for (int j = 0; j < 2; ++j) {
                int col = g*32 + j*16 + l;
                out[(size_t)b*HID + col] = anyvalid ? p[j] : 0.f;
            }
        }
    }
}

extern "C" void kernel_launch(void* const* d_in, const int* in_sizes, int n_in,
                              void* d_out, int out_size, void* d_ws, size_t ws_size,
                              hipStream_t stream)
{
    const float* k_tab = (const float*)d_in[0];
    const float* q_tab = (const float*)d_in[1];
    const float* v_tab = (const float*)d_in[2];
    const int*   nid   = (const int*)d_in[3];
    const int*   neighbors = (const int*)d_in[4];
    const float* times = (const float*)d_in[5];
    const float* rels  = (const float*)d_in[6];
    const float* t2v_w = (const float*)d_in[7];
    const float* t2v_b = (const float*)d_in[8];
    const float* tW_k  = (const float*)d_in[9];
    const float* tb_k  = (const float*)d_in[10];
    const float* tW_q  = (const float*)d_in[11];
    const float* tb_q  = (const float*)d_in[12];
    const float* tW_v  = (const float*)d_in[13];
    const float* tb_v  = (const float*)d_in[14];
    const float* rW_k  = (const float*)d_in[15];
    const float* rb_k  = (const float*)d_in[16];
    const float* rW_v  = (const float*)d_in[17];
    const float* rb_v  = (const float*)d_in[18];

    short* wfrag   = (short*)d_ws;                          // 32768 bf16 = 64KB
    float* bias_kv = (float*)((char*)d_ws + 65536);         // 256 f32
    float* q0_add  = (float*)((char*)d_ws + 65536 + 1024);  // 128 f32

    prep_kernel<<<130, 256, 0, stream>>>(t2v_w, t2v_b, tW_k, tb_k, tW_q, tb_q,
                                         tW_v, tb_v, rW_k, rb_k, rW_v, rb_v,
                                         wfrag, bias_kv, q0_add);
    aggr_kernel<<<BATCH, 512, 0, stream>>>(k_tab, q_tab, v_tab, nid, neighbors,
                                           times, rels, t2v_w, t2v_b,
                                           wfrag, bias_kv, q0_add, (float*)d_out);
}